// Round 7
// baseline (1485.291 us; speedup 1.0000x reference)
//
#include <hip/hip_runtime.h>
#include <hip/hip_fp16.h>

#define NBBITS 7
#define NBSZ   128          // nodes per bucket
#define CAP    4608         // per-bucket capacity (mean 4092, +8 sigma)

// ---------------- utility ----------------

__global__ void k_zero(float* p, int n) {
    int i = blockIdx.x * blockDim.x + threadIdx.x;
    if (i < n) p[i] = 0.0f;
}

// ---------------- bucketing ----------------

// bucket edges by dst>>7 into fixed-capacity regions, packed (src<<7)|(dst&127)
__global__ __launch_bounds__(1024) void k_bucketA(const int* __restrict__ src,
                                                  const int* __restrict__ dst,
                                                  int* __restrict__ gcnt,
                                                  int* __restrict__ bucketed,
                                                  int NB, int E) {
    __shared__ int hist[1024];
    __shared__ int base[1024];
    int tid = threadIdx.x;
    for (int i = tid; i < NB; i += 1024) hist[i] = 0;
    __syncthreads();
    int e0 = blockIdx.x * 8192;
    int e1 = min(e0 + 8192, E);
    for (int e = e0 + tid; e < e1; e += 1024)
        atomicAdd(&hist[dst[e] >> NBBITS], 1);
    __syncthreads();
    for (int i = tid; i < NB; i += 1024) {
        int h = hist[i];
        base[i] = h ? atomicAdd(&gcnt[i], h) : 0;
        hist[i] = 0;   // reuse as local cursor
    }
    __syncthreads();
    for (int e = e0 + tid; e < e1; e += 1024) {
        int d = dst[e], s = src[e];
        int b = d >> NBBITS;
        int p = base[b] + atomicAdd(&hist[b], 1);
        if (p < CAP) bucketed[b * CAP + p] = (s << NBBITS) | (d & (NBSZ - 1));
    }
}

// per-node degree -> dinv, from bucket entries (one block per bucket)
__global__ __launch_bounds__(256) void k_degdinv(const int* __restrict__ bucketed,
                                                 const int* __restrict__ gcnt,
                                                 float* __restrict__ dinv, int n) {
    __shared__ int cnt[NBSZ];
    int b = blockIdx.x, tid = threadIdx.x;
    if (tid < NBSZ) cnt[tid] = 0;
    __syncthreads();
    int c = min(gcnt[b], CAP);
    const int* ent = bucketed + (size_t)b * CAP;
    for (int i = tid; i < c; i += 256) atomicAdd(&cnt[ent[i] & (NBSZ - 1)], 1);
    __syncthreads();
    if (tid < NBSZ) {
        int node = b * NBSZ + tid;
        if (node < n) dinv[node] = rsqrtf((float)(cnt[tid] + 1));   // +1 self-loop
    }
}

// graph start offsets from sorted batch
__global__ void k_gstart(const int* __restrict__ batch, int* __restrict__ gstart,
                         int n, int G) {
    int i = blockIdx.x * blockDim.x + threadIdx.x;
    if (i > n) return;
    if (i == 0) {
        for (int g = 0; g <= batch[0]; g++) gstart[g] = 0;
    } else if (i == n) {
        for (int g = batch[n - 1] + 1; g <= G; g++) gstart[g] = n;
    } else {
        int b = batch[i], p = batch[i - 1];
        for (int g = p + 1; g <= b; g++) gstart[g] = i;
    }
}

// ---------------- compute kernels ----------------

// hs1 = fp16( (x @ W1) * dinv[row] )
__global__ __launch_bounds__(256) void k_gemm1(const float* __restrict__ x,
                                               const float* __restrict__ W,
                                               const float* __restrict__ dinv,
                                               __half* __restrict__ h, int n) {
    __shared__ float Ws[128 * 32];
    __shared__ float xs[8 * 128];
    int tid = threadIdx.x;
    for (int i = tid; i < 128 * 32; i += 256) Ws[i] = W[i];
    int rbase = blockIdx.x * 8;
    for (int i = tid; i < 8 * 128; i += 256) {
        int r = rbase + (i >> 7);
        xs[i] = (r < n) ? x[(size_t)r * 128 + (i & 127)] : 0.0f;
    }
    __syncthreads();
    int row = tid >> 5, col = tid & 31;
    float acc = 0.0f;
#pragma unroll
    for (int k = 0; k < 128; k++) acc += xs[row * 128 + k] * Ws[k * 32 + col];
    int r = rbase + row;
    if (r < n) h[(size_t)r * 32 + col] = __float2half(acc * dinv[r]);
}

// Fused bucket aggregation: one block per 128-node bucket, LDS fp32 accumulator.
// acc[dl][c] starts at self row, edge octets ds_add neighbor rows, epilogue
// applies dinv (+ optional bias/LN/ReLU/dinv) and writes fp16 rows.
template <bool DO_LN>
__global__ __launch_bounds__(512) void k_fgather(const __half* __restrict__ hs,
                                                 const int* __restrict__ bucketed,
                                                 const int* __restrict__ gcnt,
                                                 const float* __restrict__ dinv,
                                                 const float* __restrict__ b,
                                                 const float* __restrict__ g,
                                                 const float* __restrict__ be,
                                                 __half* __restrict__ out, int n) {
    __shared__ float acc[NBSZ][33];   // +1 pad: channel stride not bank-aligned
    int tid = threadIdx.x;
    int bkt = blockIdx.x;
    int node0 = bkt * NBSZ;
    const float4* hsv = (const float4*)hs;   // fp16 row = 4 float4s

    // init: 4 consecutive lanes per node, 8 channels each (self-loop term)
    int ln = tid >> 2, grp = tid & 3;
    int node = node0 + ln;
    {
        float4 raw = make_float4(0.f, 0.f, 0.f, 0.f);
        if (node < n) raw = hsv[(size_t)node * 4 + grp];
        const __half2* h2 = (const __half2*)&raw;
#pragma unroll
        for (int j = 0; j < 4; j++) {
            float2 f = __half22float2(h2[j]);
            acc[ln][grp * 8 + 2 * j]     = f.x;
            acc[ln][grp * 8 + 2 * j + 1] = f.y;
        }
    }
    __syncthreads();

    // edge phase: 64 octets, each octet covers one entry's 64B row (8B/lane)
    int c = min(gcnt[bkt], CAP);
    const int* ent = bucketed + (size_t)bkt * CAP;
    int oct = tid >> 3, l8 = tid & 7;
    for (int i = oct; i < c; i += 64) {
        int e = ent[i];
        int s = e >> NBBITS;
        int dl = e & (NBSZ - 1);
        float2 r8 = *(const float2*)(hs + (size_t)s * 32 + l8 * 4);   // 4 halfs
        const __half2* h2 = (const __half2*)&r8;
        float2 f0 = __half22float2(h2[0]);
        float2 f1 = __half22float2(h2[1]);
        int cb = l8 * 4;
        atomicAdd(&acc[dl][cb + 0], f0.x);
        atomicAdd(&acc[dl][cb + 1], f0.y);
        atomicAdd(&acc[dl][cb + 2], f1.x);
        atomicAdd(&acc[dl][cb + 3], f1.y);
    }
    __syncthreads();

    // epilogue
    if (node < n) {
        float dv = dinv[node];
        float a[8];
#pragma unroll
        for (int j = 0; j < 8; j++) a[j] = acc[ln][grp * 8 + j] * dv;
        if (DO_LN) {
            int c0 = grp * 8;
            float s = 0.f;
#pragma unroll
            for (int j = 0; j < 8; j++) { a[j] += b[c0 + j]; s += a[j]; }
#pragma unroll
            for (int m = 1; m <= 2; m <<= 1) s += __shfl_xor(s, m, 64);
            float mu = s * (1.0f / 32.0f);
            float v2 = 0.f;
#pragma unroll
            for (int j = 0; j < 8; j++) { a[j] -= mu; v2 += a[j] * a[j]; }
#pragma unroll
            for (int m = 1; m <= 2; m <<= 1) v2 += __shfl_xor(v2, m, 64);
            float inv = rsqrtf(v2 * (1.0f / 32.0f) + 1e-5f);
#pragma unroll
            for (int j = 0; j < 8; j++)
                a[j] = fmaxf(a[j] * inv * g[c0 + j] + be[c0 + j], 0.f) * dv;
        }
        __half2 o[4];
#pragma unroll
        for (int j = 0; j < 4; j++) o[j] = __floats2half2_rn(a[2 * j], a[2 * j + 1]);
        ((float4*)out)[(size_t)node * 4 + grp] = *(const float4*)o;
    }
}

// one block per graph: GEMV(32->64)+LN+ReLU per row, mean-pool, classifier MLP
__global__ __launch_bounds__(256) void k_pool_cls(const __half* __restrict__ agg2,
                                                  const float* __restrict__ W2,
                                                  const float* __restrict__ b2,
                                                  const float* __restrict__ g2,
                                                  const float* __restrict__ be2,
                                                  const int* __restrict__ gstart,
                                                  const float* __restrict__ Wc1,
                                                  const float* __restrict__ bc1,
                                                  const float* __restrict__ Wc2,
                                                  const float* __restrict__ bc2,
                                                  float* __restrict__ out) {
    __shared__ float Ws[32 * 64];   // 8 KB
    __shared__ float red[4 * 64];
    int tid = threadIdx.x;
    for (int i = tid; i < 32 * 64; i += 256) Ws[i] = W2[i];
    int g = blockIdx.x;
    int r0 = gstart[g], r1 = gstart[g + 1];
    int wave = tid >> 6, lane = tid & 63;
    float pacc = 0.0f;
    __syncthreads();
    for (int row = r0 + wave; row < r1; row += 4) {
        const __half* arow = agg2 + (size_t)row * 32;
        float acc = b2[lane];
#pragma unroll
        for (int k = 0; k < 32; k++) acc += __half2float(arow[k]) * Ws[k * 64 + lane];
        float s = acc;
#pragma unroll
        for (int m = 32; m >= 1; m >>= 1) s += __shfl_xor(s, m, 64);
        float mu = s * (1.0f / 64.0f);
        float d = acc - mu;
        float v = d * d;
#pragma unroll
        for (int m = 32; m >= 1; m >>= 1) v += __shfl_xor(v, m, 64);
        float val = d * rsqrtf(v * (1.0f / 64.0f) + 1e-5f) * g2[lane] + be2[lane];
        pacc += fmaxf(val, 0.0f);
    }
    red[wave * 64 + lane] = pacc;
    __syncthreads();
    if (wave == 0) {
        float p = red[lane] + red[64 + lane] + red[128 + lane] + red[192 + lane];
        p *= 1.0f / fmaxf((float)(r1 - r0), 1.0f);
        red[lane] = p;   // pooled row
    }
    __syncthreads();
    if (wave == 0 && lane < 32) {
        float zs = bc1[lane];
#pragma unroll
        for (int k = 0; k < 64; k++) zs += red[k] * Wc1[k * 32 + lane];
        float o = fmaxf(zs, 0.0f) * Wc2[lane];
#pragma unroll
        for (int m = 16; m >= 1; m >>= 1) o += __shfl_xor(o, m, 64);
        if (lane == 0) out[g] = o + bc2[0];
    }
}

// ---------------- launch ----------------

extern "C" void kernel_launch(void* const* d_in, const int* in_sizes, int n_in,
                              void* d_out, int out_size, void* d_ws, size_t ws_size,
                              hipStream_t stream) {
    const float* x     = (const float*)d_in[0];
    const int*   ei    = (const int*)d_in[1];
    const int*   batch = (const int*)d_in[2];
    const float* W1  = (const float*)d_in[3];
    const float* b1  = (const float*)d_in[4];
    const float* g1  = (const float*)d_in[5];
    const float* be1 = (const float*)d_in[6];
    const float* W2  = (const float*)d_in[7];
    const float* b2  = (const float*)d_in[8];
    const float* g2  = (const float*)d_in[9];
    const float* be2 = (const float*)d_in[10];
    const float* Wc1 = (const float*)d_in[11];
    const float* bc1 = (const float*)d_in[12];
    const float* Wc2 = (const float*)d_in[13];
    const float* bc2 = (const float*)d_in[14];

    int n = in_sizes[0] / 128;
    int E = in_sizes[1] / 2;
    int G = out_size;                        // 512
    int NB = (n + NBSZ - 1) / NBSZ;          // 782 buckets

    // ---- workspace layout ----
    float* ws     = (float*)d_ws;
    float* dinv   = ws;                              // n
    int*   gcnt   = (int*)(dinv + n);                // NB (<=1024)
    int*   gstart = gcnt + 1024;                     // G+1 (<=1024)
    int*   bucketed = gstart + 1024;                 // NB*CAP ints (14.4 MB)
    __half* hsA   = (__half*)(bucketed + (size_t)NB * CAP);   // n*32 halfs
    __half* hsB   = hsA + (size_t)n * 32;                     // n*32 halfs

    // zero bucket counters
    k_zero<<<(NB + 255) / 256, 256, 0, stream>>>((float*)gcnt, NB);

    // bucket edges; per-node dinv; graph ranges
    k_bucketA<<<(E + 8191) / 8192, 1024, 0, stream>>>(ei, ei + E, gcnt, bucketed, NB, E);
    k_degdinv<<<NB, 256, 0, stream>>>(bucketed, gcnt, dinv, n);
    k_gstart<<<(n + 256) / 256, 256, 0, stream>>>(batch, gstart, n, G);

    // layer 1: GEMM (128->32, dinv folded, fp16 out), fused bucket-gather + LN/ReLU/dinv
    k_gemm1<<<(n + 7) / 8, 256, 0, stream>>>(x, W1, dinv, hsA, n);
    k_fgather<true><<<NB, 512, 0, stream>>>(hsA, bucketed, gcnt, dinv,
                                            b1, g1, be1, hsB, n);

    // layer 2: fused bucket-gather (no LN), then GEMV/LN/ReLU/pool/classifier
    k_fgather<false><<<NB, 512, 0, stream>>>(hsB, bucketed, gcnt, dinv,
                                             nullptr, nullptr, nullptr, hsA, n);
    k_pool_cls<<<G, 256, 0, stream>>>(hsA, W2, b2, g2, be2, gstart,
                                      Wc1, bc1, Wc2, bc2, (float*)d_out);
}

// Round 8
// 284.098 us; speedup vs baseline: 5.2281x; 5.2281x over previous
//
#include <hip/hip_runtime.h>
#include <hip/hip_fp16.h>

#define CAP 10240      // per-coarse-bucket capacity (mean 8184, +20σ safe)

// ---------------- utility ----------------

__global__ void k_zero(float* p, int n) {
    int i = blockIdx.x * blockDim.x + threadIdx.x;
    if (i < n) p[i] = 0.0f;
}

// ---------------- CSR build: two-level counting sort ----------------

// bucket edges by dst>>8, packed (src<<8)|(dst&255)
__global__ __launch_bounds__(1024) void k_bucketA(const int* __restrict__ src,
                                                  const int* __restrict__ dst,
                                                  int* __restrict__ gcnt,
                                                  int* __restrict__ bucketed,
                                                  int NB, int E) {
    __shared__ int hist[512];
    __shared__ int base[512];
    int tid = threadIdx.x;
    for (int i = tid; i < NB; i += 1024) hist[i] = 0;
    __syncthreads();
    int e0 = blockIdx.x * 8192;
    int e1 = min(e0 + 8192, E);
    for (int e = e0 + tid; e < e1; e += 1024)
        atomicAdd(&hist[dst[e] >> 8], 1);
    __syncthreads();
    for (int i = tid; i < NB; i += 1024) {
        int h = hist[i];
        base[i] = h ? atomicAdd(&gcnt[i], h) : 0;
        hist[i] = 0;   // reuse as local cursor
    }
    __syncthreads();
    for (int e = e0 + tid; e < e1; e += 1024) {
        int d = dst[e], s = src[e];
        int b = d >> 8;
        int p = base[b] + atomicAdd(&hist[b], 1);
        if (p < CAP) bucketed[b * CAP + p] = (s << 8) | (d & 255);
    }
}

__global__ __launch_bounds__(512) void k_scan512(const int* __restrict__ in,
                                                 int* __restrict__ out, int B) {
    __shared__ int sa[512], sb[512];
    int t = threadIdx.x;
    int v = (t < B) ? in[t] : 0;
    sa[t] = v;
    __syncthreads();
    int* cur = sa;
    int* nxt = sb;
    for (int off = 1; off < 512; off <<= 1) {
        nxt[t] = cur[t] + ((t >= off) ? cur[t - off] : 0);
        __syncthreads();
        int* tmp = cur; cur = nxt; nxt = tmp;
    }
    if (t < B) out[t] = cur[t] - v;
}

// one block per bucket; fine sort by dst&255, emit csr/offs/deg/dinv (512 thr)
__global__ __launch_bounds__(512) void k_bucketB(const int* __restrict__ bucketed,
                                                 const int* __restrict__ gcnt,
                                                 const int* __restrict__ bstart,
                                                 int* __restrict__ csr,
                                                 int* __restrict__ offs,
                                                 int* __restrict__ deg,
                                                 float* __restrict__ dinv, int n) {
    __shared__ int hist[256], scan_a[256], scan_b[256];
    int b = blockIdx.x;
    int tid = threadIdx.x;
    int cnt = min(gcnt[b], CAP);
    int base = bstart[b];
    const int* ent = bucketed + (size_t)b * CAP;
    if (tid < 256) hist[tid] = 0;
    __syncthreads();
    for (int i = tid; i < cnt; i += 512) atomicAdd(&hist[ent[i] & 255], 1);
    __syncthreads();
    int h = (tid < 256) ? hist[tid] : 0;
    if (tid < 256) scan_a[tid] = h;
    __syncthreads();
    int* cur = scan_a;
    int* nxt = scan_b;
    for (int off = 1; off < 256; off <<= 1) {
        if (tid < 256) nxt[tid] = cur[tid] + ((tid >= off) ? cur[tid - off] : 0);
        __syncthreads();
        int* tmp = cur; cur = nxt; nxt = tmp;
    }
    if (tid < 256) {
        int ex = cur[tid] - h;
        int node = b * 256 + tid;
        if (node < n) {
            offs[node] = base + ex;
            deg[node] = h;
            dinv[node] = rsqrtf((float)(h + 1));   // +1 self-loop
        }
        hist[tid] = ex;      // reuse as cursor
    }
    __syncthreads();
    for (int i = tid; i < cnt; i += 512) {
        int v = ent[i];
        int p = atomicAdd(&hist[v & 255], 1);
        csr[base + p] = v >> 8;
    }
}

// graph start offsets from sorted batch
__global__ void k_gstart(const int* __restrict__ batch, int* __restrict__ gstart,
                         int n, int G) {
    int i = blockIdx.x * blockDim.x + threadIdx.x;
    if (i > n) return;
    if (i == 0) {
        for (int g = 0; g <= batch[0]; g++) gstart[g] = 0;
    } else if (i == n) {
        for (int g = batch[n - 1] + 1; g <= G; g++) gstart[g] = n;
    } else {
        int b = batch[i], p = batch[i - 1];
        for (int g = p + 1; g <= b; g++) gstart[g] = i;
    }
}

// ---------------- compute kernels ----------------

// hs1 = fp16( (x @ W1) * dinv[row] )
__global__ __launch_bounds__(256) void k_gemm1(const float* __restrict__ x,
                                               const float* __restrict__ W,
                                               const float* __restrict__ dinv,
                                               __half* __restrict__ h, int n) {
    __shared__ float Ws[128 * 32];
    __shared__ float xs[8 * 128];
    int tid = threadIdx.x;
    const float4* W4 = (const float4*)W;
    for (int i = tid; i < 32 * 32; i += 256) ((float4*)Ws)[i] = W4[i];
    int rbase = blockIdx.x * 8;
    const float4* x4 = (const float4*)x;
    for (int i = tid; i < 8 * 32; i += 256) {
        int r = rbase + (i >> 5);
        ((float4*)xs)[i] = (r < n) ? x4[(size_t)r * 32 + (i & 31)]
                                   : make_float4(0.f, 0.f, 0.f, 0.f);
    }
    __syncthreads();
    int row = tid >> 5, col = tid & 31;
    float acc = 0.0f;
#pragma unroll
    for (int k = 0; k < 128; k++) acc += xs[row * 128 + k] * Ws[k * 32 + col];
    int r = rbase + row;
    if (r < n) h[(size_t)r * 32 + col] = __float2half(acc * dinv[r]);
}

// CSR gather on fp16 rows (64 B). One 64-lane wave per row:
// lane = nb*4 + cg; nb = neighbor slot (16), cg = 16B chan group (4).
// fp32 accumulation; optional fused bias+LN+ReLU+dinv epilogue.
template <bool DO_LN>
__global__ __launch_bounds__(256) void k_gather(const __half* __restrict__ hs,
                                                const int* __restrict__ csr,
                                                const int* __restrict__ offs,
                                                const int* __restrict__ deg,
                                                const float* __restrict__ dinv,
                                                const float* __restrict__ b,
                                                const float* __restrict__ g,
                                                const float* __restrict__ be,
                                                __half* __restrict__ out, int n) {
    int wave = threadIdx.x >> 6;
    int lane = threadIdx.x & 63;
    int row = blockIdx.x * 4 + wave;
    if (row >= n) return;
    int nb = lane >> 2;       // 0..15 neighbor slot
    int cg = lane & 3;        // 0..3 chan group (8 halfs = 16 B each)
    int base = offs[row];
    int dg = deg[row];
    const float4* hsv = (const float4*)hs;   // row = 4 float4s
    float acc[8];
#pragma unroll
    for (int j = 0; j < 8; j++) acc[j] = 0.f;
    for (int it = 0; it < dg; it += 16) {
        int e = it + nb;
        if (e < dg) {
            int s = csr[base + e];
            float4 raw = hsv[(size_t)s * 4 + cg];
            const __half2* h2 = (const __half2*)&raw;
#pragma unroll
            for (int j = 0; j < 4; j++) {
                float2 f = __half22float2(h2[j]);
                acc[2 * j]     += f.x;
                acc[2 * j + 1] += f.y;
            }
        }
    }
    // reduce over the 16 neighbor slots (lane bits 2..5)
#pragma unroll
    for (int m = 4; m <= 32; m <<= 1)
#pragma unroll
        for (int j = 0; j < 8; j++) acc[j] += __shfl_xor(acc[j], m, 64);
    float dv = dinv[row];
    float4 sraw = hsv[(size_t)row * 4 + cg];
    const __half2* sh2 = (const __half2*)&sraw;
    float a[8];
#pragma unroll
    for (int j = 0; j < 4; j++) {
        float2 f = __half22float2(sh2[j]);
        a[2 * j]     = (acc[2 * j]     + f.x) * dv;
        a[2 * j + 1] = (acc[2 * j + 1] + f.y) * dv;
    }
    if (DO_LN) {
        int c0 = cg * 8;
        float s = 0.f;
#pragma unroll
        for (int j = 0; j < 8; j++) { a[j] += b[c0 + j]; s += a[j]; }
#pragma unroll
        for (int m = 1; m <= 2; m <<= 1) s += __shfl_xor(s, m, 64);
        float mu = s * (1.0f / 32.0f);
        float v2 = 0.f;
#pragma unroll
        for (int j = 0; j < 8; j++) { a[j] -= mu; v2 += a[j] * a[j]; }
#pragma unroll
        for (int m = 1; m <= 2; m <<= 1) v2 += __shfl_xor(v2, m, 64);
        float inv = rsqrtf(v2 * (1.0f / 32.0f) + 1e-5f);
#pragma unroll
        for (int j = 0; j < 8; j++)
            a[j] = fmaxf(a[j] * inv * g[c0 + j] + be[c0 + j], 0.f) * dv;
    }
    if (nb == 0) {
        __half2 o[4];
#pragma unroll
        for (int j = 0; j < 4; j++) o[j] = __floats2half2_rn(a[2 * j], a[2 * j + 1]);
        ((float4*)out)[(size_t)row * 4 + cg] = *(const float4*)o;
    }
}

// one block per graph: GEMV(32->64)+LN+ReLU per row, mean-pool, classifier MLP
__global__ __launch_bounds__(256) void k_pool_cls(const __half* __restrict__ agg2,
                                                  const float* __restrict__ W2,
                                                  const float* __restrict__ b2,
                                                  const float* __restrict__ g2,
                                                  const float* __restrict__ be2,
                                                  const int* __restrict__ gstart,
                                                  const float* __restrict__ Wc1,
                                                  const float* __restrict__ bc1,
                                                  const float* __restrict__ Wc2,
                                                  const float* __restrict__ bc2,
                                                  float* __restrict__ out) {
    __shared__ float Ws[32 * 64];   // 8 KB
    __shared__ float red[4 * 64];
    int tid = threadIdx.x;
    for (int i = tid; i < 32 * 64; i += 256) Ws[i] = W2[i];
    int g = blockIdx.x;
    int r0 = gstart[g], r1 = gstart[g + 1];
    int wave = tid >> 6, lane = tid & 63;
    float pacc = 0.0f;
    __syncthreads();
    for (int row = r0 + wave; row < r1; row += 4) {
        const __half* arow = agg2 + (size_t)row * 32;
        float acc = b2[lane];
#pragma unroll
        for (int k = 0; k < 32; k++) acc += __half2float(arow[k]) * Ws[k * 64 + lane];
        float s = acc;
#pragma unroll
        for (int m = 32; m >= 1; m >>= 1) s += __shfl_xor(s, m, 64);
        float mu = s * (1.0f / 64.0f);
        float d = acc - mu;
        float v = d * d;
#pragma unroll
        for (int m = 32; m >= 1; m >>= 1) v += __shfl_xor(v, m, 64);
        float val = d * rsqrtf(v * (1.0f / 64.0f) + 1e-5f) * g2[lane] + be2[lane];
        pacc += fmaxf(val, 0.0f);
    }
    red[wave * 64 + lane] = pacc;
    __syncthreads();
    if (wave == 0) {
        float p = red[lane] + red[64 + lane] + red[128 + lane] + red[192 + lane];
        p *= 1.0f / fmaxf((float)(r1 - r0), 1.0f);
        red[lane] = p;   // pooled row
    }
    __syncthreads();
    if (wave == 0 && lane < 32) {
        float zs = bc1[lane];
#pragma unroll
        for (int k = 0; k < 64; k++) zs += red[k] * Wc1[k * 32 + lane];
        float o = fmaxf(zs, 0.0f) * Wc2[lane];
#pragma unroll
        for (int m = 16; m >= 1; m >>= 1) o += __shfl_xor(o, m, 64);
        if (lane == 0) out[g] = o + bc2[0];
    }
}

// ---------------- launch ----------------

extern "C" void kernel_launch(void* const* d_in, const int* in_sizes, int n_in,
                              void* d_out, int out_size, void* d_ws, size_t ws_size,
                              hipStream_t stream) {
    const float* x     = (const float*)d_in[0];
    const int*   ei    = (const int*)d_in[1];
    const int*   batch = (const int*)d_in[2];
    const float* W1  = (const float*)d_in[3];
    const float* b1  = (const float*)d_in[4];
    const float* g1  = (const float*)d_in[5];
    const float* be1 = (const float*)d_in[6];
    const float* W2  = (const float*)d_in[7];
    const float* b2  = (const float*)d_in[8];
    const float* g2  = (const float*)d_in[9];
    const float* be2 = (const float*)d_in[10];
    const float* Wc1 = (const float*)d_in[11];
    const float* bc1 = (const float*)d_in[12];
    const float* Wc2 = (const float*)d_in[13];
    const float* bc2 = (const float*)d_in[14];

    int n = in_sizes[0] / 128;
    int E = in_sizes[1] / 2;
    int G = out_size;                  // 512
    int n32 = n * 32;
    int NB = (n + 255) >> 8;           // coarse buckets (391 <= 512)

    // ---- workspace layout ----
    float* ws     = (float*)d_ws;
    float* dinv   = ws;                          // n
    int*   deg    = (int*)(dinv + n);            // n
    int*   offs   = deg + n;                     // n
    int*   gcnt   = offs + n;                    // 512
    int*   bstart = gcnt + 512;                  // 512
    int*   gstart = bstart + 512;                // 516 (padded for 16B alignment)
    int*   csr    = gstart + 516;                // E (16B-aligned)
    float* hsAf   = (float*)(csr + E);           // n*32 fp32-sized region
    float* hsBf   = hsAf + (size_t)n32;          // n*32
    __half* hsA   = (__half*)hsAf;
    __half* hsB   = (__half*)hsBf;
    int*   bucketed = (int*)hsAf;                // overlay: NB*CAP ints (16MB < 25.6MB)

    // zero bucket counters
    k_zero<<<(NB + 255) / 256, 256, 0, stream>>>((float*)gcnt, NB);

    // CSR build (two-level counting sort) + dinv; graph ranges
    k_bucketA<<<(E + 8191) / 8192, 1024, 0, stream>>>(ei, ei + E, gcnt, bucketed, NB, E);
    k_scan512<<<1, 512, 0, stream>>>(gcnt, bstart, NB);
    k_bucketB<<<NB, 512, 0, stream>>>(bucketed, gcnt, bstart, csr, offs, deg, dinv, n);
    k_gstart<<<(n + 256) / 256, 256, 0, stream>>>(batch, gstart, n, G);

    // layer 1: GEMM (128->32, dinv folded, fp16 out), gather + fused LN/ReLU/dinv
    k_gemm1<<<(n + 7) / 8, 256, 0, stream>>>(x, W1, dinv, hsA, n);
    k_gather<true><<<(n + 3) / 4, 256, 0, stream>>>(hsA, csr, offs, deg, dinv,
                                                    b1, g1, be1, hsB, n);

    // layer 2: gather first (32 ch), then fused GEMV/LN/ReLU/pool/classifier
    k_gather<false><<<(n + 3) / 4, 256, 0, stream>>>(hsB, csr, offs, deg, dinv,
                                                     nullptr, nullptr, nullptr, hsA, n);
    k_pool_cls<<<G, 256, 0, stream>>>(hsA, W2, b2, g2, be2, gstart,
                                      Wc1, bc1, Wc2, bc2, (float*)d_out);
}

// Round 9
// 234.691 us; speedup vs baseline: 6.3287x; 1.2105x over previous
//
#include <hip/hip_runtime.h>
#include <hip/hip_fp16.h>

#define CAP 10240      // per-coarse-bucket capacity (mean 8184, +20σ safe)

// ---------------- fused: bucketA | gemm1(no dinv) | gstart ----------------
// blocks [0,nA): bucket edges by dst>>8, packed (src<<8)|(dst&255)
// blocks [nA,nA+nG1): hs1 = fp16(x @ W1), 32 rows/block
// blocks [nA+nG1,...): gstart from sorted batch
__global__ __launch_bounds__(1024) void k_fused1(const int* __restrict__ ei,
                                                 const float* __restrict__ x,
                                                 const float* __restrict__ W1,
                                                 const int* __restrict__ batch,
                                                 int* __restrict__ gcnt,
                                                 int* __restrict__ bucketed,
                                                 __half* __restrict__ hs,
                                                 int* __restrict__ gstart,
                                                 int nA, int nG1, int NB,
                                                 int n, int E, int G) {
    __shared__ __align__(16) char smem[32768];
    int tid = threadIdx.x;
    int bid = blockIdx.x;
    if (bid < nA) {
        // ---- bucketA ----
        int* hist = (int*)smem;          // 512
        int* base = (int*)(smem + 2048); // 512
        const int* src = ei;
        const int* dst = ei + E;
        for (int i = tid; i < NB; i += 1024) hist[i] = 0;
        __syncthreads();
        int e0 = bid * 8192;
        int e1 = min(e0 + 8192, E);
        for (int e = e0 + tid; e < e1; e += 1024)
            atomicAdd(&hist[dst[e] >> 8], 1);
        __syncthreads();
        for (int i = tid; i < NB; i += 1024) {
            int h = hist[i];
            base[i] = h ? atomicAdd(&gcnt[i], h) : 0;
            hist[i] = 0;   // local cursor
        }
        __syncthreads();
        for (int e = e0 + tid; e < e1; e += 1024) {
            int d = dst[e], s = src[e];
            int b = d >> 8;
            int p = base[b] + atomicAdd(&hist[b], 1);
            if (p < CAP) bucketed[(size_t)b * CAP + p] = (s << 8) | (d & 255);
        }
    } else if (bid < nA + nG1) {
        // ---- gemm1 (unscaled) ----
        float* Ws = (float*)smem;            // 128*32
        float* xs = (float*)(smem + 16384);  // 32*128
        int gb = bid - nA;
        const float4* W4 = (const float4*)W1;
        ((float4*)Ws)[tid] = W4[tid];        // 1024 float4s, one per thread
        int rbase = gb * 32;
        const float4* x4 = (const float4*)x;
        {
            int r = rbase + (tid >> 5);
            ((float4*)xs)[tid] = (r < n) ? x4[(size_t)r * 32 + (tid & 31)]
                                         : make_float4(0.f, 0.f, 0.f, 0.f);
        }
        __syncthreads();
        int row = tid >> 5, col = tid & 31;
        float acc = 0.0f;
#pragma unroll
        for (int k = 0; k < 128; k++) acc += xs[row * 128 + k] * Ws[k * 32 + col];
        int r = rbase + row;
        if (r < n) hs[(size_t)r * 32 + col] = __float2half(acc);
    } else {
        // ---- gstart ----
        int i = (bid - nA - nG1) * 1024 + tid;
        if (i > n) return;
        if (i == 0) {
            for (int g = 0; g <= batch[0]; g++) gstart[g] = 0;
        } else if (i == n) {
            for (int g = batch[n - 1] + 1; g <= G; g++) gstart[g] = n;
        } else {
            int b = batch[i], p = batch[i - 1];
            for (int g = p + 1; g <= b; g++) gstart[g] = i;
        }
    }
}

// ---------------- bucketB: fine sort + deg/dinv/offs + hs dinv-scale ----------------
__global__ __launch_bounds__(512) void k_bucketB(const int* __restrict__ bucketed,
                                                 const int* __restrict__ gcnt,
                                                 int* __restrict__ csr,
                                                 int* __restrict__ offs,
                                                 int* __restrict__ deg,
                                                 float* __restrict__ dinv,
                                                 __half* __restrict__ hs, int n) {
    __shared__ int hist[256], scan_a[256], scan_b[256];
    __shared__ float sdinv[256];
    int b = blockIdx.x;
    int tid = threadIdx.x;
    int cnt = min(gcnt[b], CAP);
    int base = b * CAP;                       // fixed-stride csr, no scan needed
    const int* ent = bucketed + (size_t)b * CAP;
    if (tid < 256) hist[tid] = 0;
    __syncthreads();
    for (int i = tid; i < cnt; i += 512) atomicAdd(&hist[ent[i] & 255], 1);
    __syncthreads();
    int h = (tid < 256) ? hist[tid] : 0;
    if (tid < 256) scan_a[tid] = h;
    __syncthreads();
    int* cur = scan_a;
    int* nxt = scan_b;
    for (int off = 1; off < 256; off <<= 1) {
        if (tid < 256) nxt[tid] = cur[tid] + ((tid >= off) ? cur[tid - off] : 0);
        __syncthreads();
        int* tmp = cur; cur = nxt; nxt = tmp;
    }
    if (tid < 256) {
        int ex = cur[tid] - h;
        float dv = rsqrtf((float)(h + 1));    // +1 self-loop
        sdinv[tid] = dv;
        int node = b * 256 + tid;
        if (node < n) {
            offs[node] = base + ex;
            deg[node] = h;
            dinv[node] = dv;
        }
        hist[tid] = ex;      // reuse as cursor
    }
    __syncthreads();
    for (int i = tid; i < cnt; i += 512) {
        int v = ent[i];
        int p = atomicAdd(&hist[v & 255], 1);
        csr[base + p] = v >> 8;
    }
    // scale this block's 256 hs rows by dinv (independent of scatter above)
    float4* hsv = (float4*)hs;
#pragma unroll
    for (int p = 0; p < 2; p++) {
        int idx = p * 512 + tid;              // 1024 units = 256 nodes * 4 cg
        int nl = idx >> 2, cg = idx & 3;
        int node = b * 256 + nl;
        if (node < n) {
            float dv = sdinv[nl];
            float4 raw = hsv[(size_t)node * 4 + cg];
            __half2* h2 = (__half2*)&raw;
            __half2 o[4];
#pragma unroll
            for (int j = 0; j < 4; j++) {
                float2 f = __half22float2(h2[j]);
                o[j] = __floats2half2_rn(f.x * dv, f.y * dv);
            }
            hsv[(size_t)node * 4 + cg] = *(const float4*)o;
        }
    }
}

// ---------------- CSR gather (fp16 rows, fp32 accum) ----------------
// one 64-lane wave per row: lane = nb*4 + cg; 16 neighbor slots x 16B chan groups
template <bool DO_LN>
__global__ __launch_bounds__(256) void k_gather(const __half* __restrict__ hs,
                                                const int* __restrict__ csr,
                                                const int* __restrict__ offs,
                                                const int* __restrict__ deg,
                                                const float* __restrict__ dinv,
                                                const float* __restrict__ b,
                                                const float* __restrict__ g,
                                                const float* __restrict__ be,
                                                __half* __restrict__ out, int n) {
    int wave = threadIdx.x >> 6;
    int lane = threadIdx.x & 63;
    int row = blockIdx.x * 4 + wave;
    if (row >= n) return;
    int nb = lane >> 2;       // 0..15 neighbor slot
    int cg = lane & 3;        // 0..3 chan group
    int base = offs[row];
    int dg = deg[row];
    const float4* hsv = (const float4*)hs;
    float acc[8];
#pragma unroll
    for (int j = 0; j < 8; j++) acc[j] = 0.f;
    int nfull = dg & ~15;
    for (int it = 0; it < nfull; it += 16) {      // branch-free main loop
        int s = csr[base + it + nb];
        float4 raw = hsv[(size_t)s * 4 + cg];
        const __half2* h2 = (const __half2*)&raw;
#pragma unroll
        for (int j = 0; j < 4; j++) {
            float2 f = __half22float2(h2[j]);
            acc[2 * j]     += f.x;
            acc[2 * j + 1] += f.y;
        }
    }
    if (nfull + nb < dg) {                         // tail
        int s = csr[base + nfull + nb];
        float4 raw = hsv[(size_t)s * 4 + cg];
        const __half2* h2 = (const __half2*)&raw;
#pragma unroll
        for (int j = 0; j < 4; j++) {
            float2 f = __half22float2(h2[j]);
            acc[2 * j]     += f.x;
            acc[2 * j + 1] += f.y;
        }
    }
#pragma unroll
    for (int m = 4; m <= 32; m <<= 1)
#pragma unroll
        for (int j = 0; j < 8; j++) acc[j] += __shfl_xor(acc[j], m, 64);
    float dv = dinv[row];
    float4 sraw = hsv[(size_t)row * 4 + cg];
    const __half2* sh2 = (const __half2*)&sraw;
    float a[8];
#pragma unroll
    for (int j = 0; j < 4; j++) {
        float2 f = __half22float2(sh2[j]);
        a[2 * j]     = (acc[2 * j]     + f.x) * dv;
        a[2 * j + 1] = (acc[2 * j + 1] + f.y) * dv;
    }
    if (DO_LN) {
        int c0 = cg * 8;
        float s = 0.f;
#pragma unroll
        for (int j = 0; j < 8; j++) { a[j] += b[c0 + j]; s += a[j]; }
#pragma unroll
        for (int m = 1; m <= 2; m <<= 1) s += __shfl_xor(s, m, 64);
        float mu = s * (1.0f / 32.0f);
        float v2 = 0.f;
#pragma unroll
        for (int j = 0; j < 8; j++) { a[j] -= mu; v2 += a[j] * a[j]; }
#pragma unroll
        for (int m = 1; m <= 2; m <<= 1) v2 += __shfl_xor(v2, m, 64);
        float inv = rsqrtf(v2 * (1.0f / 32.0f) + 1e-5f);
#pragma unroll
        for (int j = 0; j < 8; j++)
            a[j] = fmaxf(a[j] * inv * g[c0 + j] + be[c0 + j], 0.f) * dv;
    }
    if (nb == 0) {
        __half2 o[4];
#pragma unroll
        for (int j = 0; j < 4; j++) o[j] = __floats2half2_rn(a[2 * j], a[2 * j + 1]);
        ((float4*)out)[(size_t)row * 4 + cg] = *(const float4*)o;
    }
}

// ---------------- pool + classifier (512 thr: 8 rows in flight) ----------------
__global__ __launch_bounds__(512) void k_pool_cls(const __half* __restrict__ agg2,
                                                  const float* __restrict__ W2,
                                                  const float* __restrict__ b2,
                                                  const float* __restrict__ g2,
                                                  const float* __restrict__ be2,
                                                  const int* __restrict__ gstart,
                                                  const float* __restrict__ Wc1,
                                                  const float* __restrict__ bc1,
                                                  const float* __restrict__ Wc2,
                                                  const float* __restrict__ bc2,
                                                  float* __restrict__ out) {
    __shared__ float Ws[32 * 64];   // 8 KB
    __shared__ float red[8 * 64];
    int tid = threadIdx.x;
    for (int i = tid; i < 32 * 64; i += 512) Ws[i] = W2[i];
    int g = blockIdx.x;
    int r0 = gstart[g], r1 = gstart[g + 1];
    int wave = tid >> 6, lane = tid & 63;
    float pacc = 0.0f;
    __syncthreads();
    for (int row = r0 + wave; row < r1; row += 8) {
        const float4* a4 = (const float4*)(agg2 + (size_t)row * 32);
        float4 r4[4];
#pragma unroll
        for (int q = 0; q < 4; q++) r4[q] = a4[q];
        const __half2* ah = (const __half2*)r4;
        float acc = b2[lane];
#pragma unroll
        for (int k2 = 0; k2 < 16; k2++) {
            float2 f = __half22float2(ah[k2]);
            acc += f.x * Ws[(2 * k2) * 64 + lane] + f.y * Ws[(2 * k2 + 1) * 64 + lane];
        }
        float s = acc;
#pragma unroll
        for (int m = 32; m >= 1; m >>= 1) s += __shfl_xor(s, m, 64);
        float mu = s * (1.0f / 64.0f);
        float d = acc - mu;
        float v = d * d;
#pragma unroll
        for (int m = 32; m >= 1; m >>= 1) v += __shfl_xor(v, m, 64);
        float val = d * rsqrtf(v * (1.0f / 64.0f) + 1e-5f) * g2[lane] + be2[lane];
        pacc += fmaxf(val, 0.0f);
    }
    red[wave * 64 + lane] = pacc;
    __syncthreads();
    if (wave == 0) {
        float p = 0.f;
#pragma unroll
        for (int w = 0; w < 8; w++) p += red[w * 64 + lane];
        p *= 1.0f / fmaxf((float)(r1 - r0), 1.0f);
        red[lane] = p;   // pooled row
    }
    __syncthreads();
    if (wave == 0 && lane < 32) {
        float zs = bc1[lane];
#pragma unroll
        for (int k = 0; k < 64; k++) zs += red[k] * Wc1[k * 32 + lane];
        float o = fmaxf(zs, 0.0f) * Wc2[lane];
#pragma unroll
        for (int m = 16; m >= 1; m >>= 1) o += __shfl_xor(o, m, 64);
        if (lane == 0) out[g] = o + bc2[0];
    }
}

// ---------------- launch ----------------

extern "C" void kernel_launch(void* const* d_in, const int* in_sizes, int n_in,
                              void* d_out, int out_size, void* d_ws, size_t ws_size,
                              hipStream_t stream) {
    const float* x     = (const float*)d_in[0];
    const int*   ei    = (const int*)d_in[1];
    const int*   batch = (const int*)d_in[2];
    const float* W1  = (const float*)d_in[3];
    const float* b1  = (const float*)d_in[4];
    const float* g1  = (const float*)d_in[5];
    const float* be1 = (const float*)d_in[6];
    const float* W2  = (const float*)d_in[7];
    const float* b2  = (const float*)d_in[8];
    const float* g2  = (const float*)d_in[9];
    const float* be2 = (const float*)d_in[10];
    const float* Wc1 = (const float*)d_in[11];
    const float* bc1 = (const float*)d_in[12];
    const float* Wc2 = (const float*)d_in[13];
    const float* bc2 = (const float*)d_in[14];

    int n = in_sizes[0] / 128;
    int E = in_sizes[1] / 2;
    int G = out_size;                  // 512
    int NB = (n + 255) >> 8;           // 391 coarse buckets

    // ---- workspace layout (~39.6 MB) ----
    float* ws     = (float*)d_ws;
    float* dinv   = ws;                               // n
    int*   deg    = (int*)(dinv + n);                 // n
    int*   offs   = deg + n;                          // n
    int*   gcnt   = offs + n;                         // 512
    int*   gstart = gcnt + 512;                       // 516 (pad, 16B align)
    int*   csr    = gstart + 516;                     // NB*CAP (16 MB)
    __half* hsA   = (__half*)(csr + (size_t)NB * CAP);        // n*32 halfs (6.4 MB)
    int*   bucketed = (int*)(hsA + (size_t)n * 32);   // NB*CAP (16 MB)
    __half* hsB   = (__half*)bucketed;                // overlays bucketed (dead after bucketB)

    int nA  = (E + 8191) / 8192;       // 391
    int nG1 = (n + 31) / 32;           // 3125
    int nGs = (n + 1024) / 1024;       // 98

    hipMemsetAsync(gcnt, 0, NB * sizeof(int), stream);

    // K1: bucketA | gemm1(unscaled) | gstart
    k_fused1<<<nA + nG1 + nGs, 1024, 0, stream>>>(ei, x, W1, batch, gcnt, bucketed,
                                                  hsA, gstart, nA, nG1, NB, n, E, G);
    // K2: fine sort -> csr/offs/deg/dinv, + scale hsA rows by dinv
    k_bucketB<<<NB, 512, 0, stream>>>(bucketed, gcnt, csr, offs, deg, dinv, hsA, n);

    // K3: layer-1 aggregate + fused bias/LN/ReLU/dinv -> hsB
    k_gather<true><<<(n + 3) / 4, 256, 0, stream>>>(hsA, csr, offs, deg, dinv,
                                                    b1, g1, be1, hsB, n);
    // K4: layer-2 aggregate -> agg2 (into hsA region)
    k_gather<false><<<(n + 3) / 4, 256, 0, stream>>>(hsB, csr, offs, deg, dinv,
                                                     nullptr, nullptr, nullptr, hsA, n);
    // K5: GEMV+LN+ReLU+mean-pool+classifier
    k_pool_cls<<<G, 512, 0, stream>>>(hsA, W2, b2, g2, be2, gstart,
                                      Wc1, bc1, Wc2, bc2, (float*)d_out);
}